// Round 4
// baseline (1984.856 us; speedup 1.0000x reference)
//
#include <hip/hip_runtime.h>
#include <hip/hip_bf16.h>
#include <hip/hip_fp16.h>

typedef __attribute__((ext_vector_type(8))) short short8;
typedef __attribute__((ext_vector_type(4))) float f32x4;
typedef __attribute__((ext_vector_type(4))) unsigned int u32x4;

#define Hh 512
#define Bb 64
#define Ss 512
#define Gg 2048
#define NROW 32768

static __device__ inline short f2bf(float f) {
    union { float f; unsigned u; } v; v.f = f;
    unsigned r = (v.u + 0x7FFFu + ((v.u >> 16) & 1u)) >> 16;
    return (short)r;
}

static __device__ inline short8 pack_bf8(const float* p) {
    f32x4 u0 = *(const f32x4*)p;
    f32x4 u1 = *(const f32x4*)(p + 4);
    short8 t;
    t[0] = f2bf(u0[0]); t[1] = f2bf(u0[1]); t[2] = f2bf(u0[2]); t[3] = f2bf(u0[3]);
    t[4] = f2bf(u1[0]); t[5] = f2bf(u1[1]); t[6] = f2bf(u1[2]); t[7] = f2bf(u1[3]);
    return t;
}

static __device__ inline float fsigmoid(float x) {
    return __builtin_amdgcn_rcpf(1.f + __builtin_amdgcn_exp2f(x * -1.44269504088896f));
}
static __device__ inline float ftanh(float x) {
    float xc = fminf(fmaxf(x, -15.f), 15.f);
    float e = __builtin_amdgcn_exp2f(xc * 2.88539008177793f); // e^(2x)
    return (e - 1.f) / (e + 1.f);
}

// ---------------- prep: f32 -> bf16 for W_ih and fc_W ----------------
__global__ __launch_bounds__(256)
void prep_bf16(const float* __restrict__ wih, const float* __restrict__ fcw,
               short* __restrict__ wih_bf, short* __restrict__ fcw_bf) {
    const int n1 = Gg * 256;
    const int n2 = 48 * Hh;
    for (int i = blockIdx.x * blockDim.x + threadIdx.x; i < n1 + n2;
         i += gridDim.x * blockDim.x) {
        if (i < n1) wih_bf[i] = f2bf(wih[i]);
        else        fcw_bf[i - n1] = f2bf(fcw[i - n1]);
    }
}

// ---------------- px[t][b][g] = (emb[x] @ W_ih^T + b_hh)  (fp16) ----------------
__global__ __launch_bounds__(256)
void px_kernel(const int* __restrict__ x, const float* __restrict__ emb,
               const short* __restrict__ wih_bf, const float* __restrict__ bhh,
               _Float16* __restrict__ px) {
    const int w = threadIdx.x >> 6, lane = threadIdx.x & 63;
    const int lr = lane & 15, lc = lane >> 4;
    const int r0 = blockIdx.x * 64 + w * 16;

    short8 a[8];
    const int tok = x[r0 + lr];
    const float* arow = emb + (long)tok * 256;
#pragma unroll
    for (int ks = 0; ks < 8; ks++)
        a[ks] = pack_bf8(arow + ks * 32 + lc * 8);

    for (int g0 = 0; g0 < Gg; g0 += 16) {
        f32x4 acc = {0.f, 0.f, 0.f, 0.f};
#pragma unroll
        for (int ks = 0; ks < 8; ks++) {
            short8 b = *(const short8*)(wih_bf + (g0 + lr) * 256 + ks * 32 + lc * 8);
            acc = __builtin_amdgcn_mfma_f32_16x16x32_bf16(a[ks], b, acc, 0, 0, 0);
        }
        const float bias = bhh[g0 + lr];
#pragma unroll
        for (int i = 0; i < 4; i++) {
            const int r = r0 + lc * 4 + i;          // global row = b*S + s
            const int bb = r >> 9, s = r & 511;
            px[((long)s * Bb + bb) * Gg + g0 + lr] = (_Float16)(acc[i] + bias);
        }
    }
}

// ---------------- persistent LSTM recurrence, tag-polled exchange ----------------
// 32 WGs x 512 thr. cluster cl = blockIdx&3 (16 batches), wgc = blockIdx>>2 (64 cols).
// h exchange: tagged u32 (tag<<16 | h_bf16) in hbufT[2][64][512]; consumers poll the
// data dwords until tag==t (dword atomicity => self-validating, no flags, no ack wait).
__global__ __launch_bounds__(512)
void lstm_kernel(const float* __restrict__ whh, const _Float16* __restrict__ px,
                 unsigned int* __restrict__ hbufT,    // [2][64][512] tagged u32
                 unsigned int* __restrict__ hs32) {   // [32768][256] packed bf16x2
    const int cl  = blockIdx.x & 3;
    const int wgc = blockIdx.x >> 2;       // 0..7
    const int b0 = cl * 16;
    const int J0 = wgc * 64;
    const int w = threadIdx.x >> 6;        // 0..7
    const int lane = threadIdx.x & 63;
    const int lr = lane & 15, lc = lane >> 4;
    const int gt = w & 3;
    const int Jsub = (w >> 2) * 32;

    __shared__ float gates[4][16][66];                     // padded: no 4-way conflict
    __shared__ __align__(16) unsigned int hlds[16 * 256];  // 16 KB, swizzled bf16 pairs

    // W_hh fragments resident in VGPRs: 2 tiles x 16 k-steps
    short8 wf[2][16];
#pragma unroll
    for (int u = 0; u < 2; u++)
#pragma unroll
        for (int ks = 0; ks < 16; ks++)
            wf[u][ks] = pack_bf8(whh + (long)(gt * Hh + J0 + Jsub + u * 16 + lr) * Hh + ks * 32 + lc * 8);

    // cell state in registers: thread owns (eb, 2*jp), (eb, 2*jp+1)
    const int eb = threadIdx.x >> 5;       // 0..15
    const int jp = threadIdx.x & 31;
    float c0 = 0.f, c1 = 0.f;

    const int gr0 = gt * Hh + J0 + Jsub + lr;
    float pf[2][4];
#pragma unroll
    for (int u = 0; u < 2; u++)
#pragma unroll
        for (int i = 0; i < 4; i++)
            pf[u][i] = (float)px[((long)0 * Bb + b0 + lc * 4 + i) * Gg + gr0 + u * 16];

    // poll-chunk mapping: thread -> (row, 16 cols)
    const int prow = threadIdx.x >> 5;     // 0..15
    const int pcg  = threadIdx.x & 31;     // 16-col group
    const int csw  = (prow & 7) << 2;      // LDS swizzle for this row
    const int li0  = prow * 256 + ((pcg * 8) ^ csw);
    const int li1  = prow * 256 + ((pcg * 8 + 4) ^ csw);

#pragma unroll 1
    for (int t = 0; t < Ss; t++) {
        if (t == 0) {
            u32x4 z = {0u, 0u, 0u, 0u};
            *(u32x4*)&hlds[li0] = z;
            *(u32x4*)&hlds[li1] = z;
        } else {
            unsigned long long* pp = (unsigned long long*)
                (hbufT + (t & 1) * (Bb * Hh) + (b0 + prow) * Hh + pcg * 16);
            const unsigned long long want2 =
                ((unsigned long long)(unsigned)t << 48) | ((unsigned long long)(unsigned)t << 16);
            unsigned long long q[8];
            unsigned long long bad;
            do {
                bad = 0;
#pragma unroll
                for (int i = 0; i < 8; i++)
                    q[i] = __hip_atomic_load(pp + i, __ATOMIC_RELAXED, __HIP_MEMORY_SCOPE_AGENT);
#pragma unroll
                for (int i = 0; i < 8; i++)
                    bad |= (q[i] ^ want2) & 0xFFFF0000FFFF0000ull;
            } while (bad);
            // strip tags -> packed bf16 pairs, write swizzled LDS
            unsigned pk[8];
#pragma unroll
            for (int i = 0; i < 8; i++)
                pk[i] = (unsigned)(q[i] & 0xFFFFu) | (((unsigned)(q[i] >> 32) & 0xFFFFu) << 16);
            u32x4 v0 = {pk[0], pk[1], pk[2], pk[3]};
            u32x4 v1 = {pk[4], pk[5], pk[6], pk[7]};
            *(u32x4*)&hlds[li0] = v0;
            *(u32x4*)&hlds[li1] = v1;
        }
        __syncthreads();   // A: h tile ready (also drains last iter's stores ~free)

        f32x4 acc[2];
#pragma unroll
        for (int u = 0; u < 2; u++) {
            acc[u][0] = pf[u][0]; acc[u][1] = pf[u][1];
            acc[u][2] = pf[u][2]; acc[u][3] = pf[u][3];
        }
#pragma unroll
        for (int ks = 0; ks < 16; ks++) {
            const int c = ks * 16 + lc * 4;
            const short8 af = *(const short8*)&hlds[lr * 256 + (c ^ ((lr & 7) << 2))];
            acc[0] = __builtin_amdgcn_mfma_f32_16x16x32_bf16(af, wf[0][ks], acc[0], 0, 0, 0);
            acc[1] = __builtin_amdgcn_mfma_f32_16x16x32_bf16(af, wf[1][ks], acc[1], 0, 0, 0);
        }

#pragma unroll
        for (int u = 0; u < 2; u++)
#pragma unroll
            for (int i = 0; i < 4; i++)
                gates[gt][lc * 4 + i][Jsub + u * 16 + lr] = acc[u][i];
        __syncthreads();   // B: gates ready

        // elementwise cell update; tagged h store (fire-and-forget) + history store
        {
            const int j = jp * 2;
            const float gi0 = gates[0][eb][j],   gi1 = gates[0][eb][j + 1];
            const float gf0 = gates[1][eb][j],   gf1 = gates[1][eb][j + 1];
            const float gg0 = gates[2][eb][j],   gg1 = gates[2][eb][j + 1];
            const float go0 = gates[3][eb][j],   go1 = gates[3][eb][j + 1];
            c0 = fsigmoid(gf0) * c0 + fsigmoid(gi0) * ftanh(gg0);
            c1 = fsigmoid(gf1) * c1 + fsigmoid(gi1) * ftanh(gg1);
            const float h0 = fsigmoid(go0) * ftanh(c0);
            const float h1 = fsigmoid(go1) * ftanh(c1);
            const unsigned hb0 = (unsigned)(unsigned short)f2bf(h0);
            const unsigned hb1 = (unsigned)(unsigned short)f2bf(h1);
            const unsigned tag = (unsigned)(t + 1) << 16;
            const unsigned long long hv =
                (unsigned long long)(hb0 | tag) |
                ((unsigned long long)(hb1 | tag) << 32);
            unsigned long long* hw = (unsigned long long*)
                (hbufT + ((t + 1) & 1) * (Bb * Hh) + (b0 + eb) * Hh + J0 + j);
            __hip_atomic_store(hw, hv, __ATOMIC_RELAXED, __HIP_MEMORY_SCOPE_AGENT);
            hs32[((long)(b0 + eb) * Ss + t) * 256 + (J0 >> 1) + jp] = hb0 | (hb1 << 16);
        }

        // off the critical path: px prefetch for t+1 (drains under next poll)
        const int tn = (t + 1 < Ss) ? t + 1 : t;
#pragma unroll
        for (int u = 0; u < 2; u++)
#pragma unroll
            for (int i = 0; i < 4; i++)
                pf[u][i] = (float)px[((long)tn * Bb + b0 + lc * 4 + i) * Gg + gr0 + u * 16];
    }
}

// ---------------- logits = hs @ fc_W^T + fc_b, then log_softmax ----------------
__global__ __launch_bounds__(256)
void fc_kernel(const unsigned short* __restrict__ hs, const short* __restrict__ fcw_bf,
               const float* __restrict__ fcb, float* __restrict__ out) {
    const int w = threadIdx.x >> 6, lane = threadIdx.x & 63;
    const int lr = lane & 15, lc = lane >> 4;
    const int r0 = blockIdx.x * 64 + w * 16;

    short8 af[16];
#pragma unroll
    for (int ks = 0; ks < 16; ks++)
        af[ks] = *(const short8*)((const short*)hs + (long)(r0 + lr) * Hh + ks * 32 + lc * 8);

    f32x4 acc[3];
#pragma unroll
    for (int nt = 0; nt < 3; nt++) {
        f32x4 a_ = {0.f, 0.f, 0.f, 0.f};
#pragma unroll
        for (int ks = 0; ks < 16; ks++) {
            short8 b = *(const short8*)(fcw_bf + (nt * 16 + lr) * Hh + ks * 32 + lc * 8);
            a_ = __builtin_amdgcn_mfma_f32_16x16x32_bf16(af[ks], b, a_, 0, 0, 0);
        }
        acc[nt] = a_;
    }

    const float bb0 = fcb[lr], bb1 = fcb[16 + lr], bb2 = fcb[32 + lr];
#pragma unroll
    for (int i = 0; i < 4; i++) {
        float v0 = acc[0][i] + bb0, v1 = acc[1][i] + bb1, v2 = acc[2][i] + bb2;
        float m = fmaxf(v0, fmaxf(v1, v2));
#pragma unroll
        for (int d = 1; d < 16; d <<= 1) m = fmaxf(m, __shfl_xor(m, d));
        float s = expf(v0 - m) + expf(v1 - m) + expf(v2 - m);
#pragma unroll
        for (int d = 1; d < 16; d <<= 1) s += __shfl_xor(s, d);
        const float lse = m + logf(s);
        const long r = r0 + lc * 4 + i;
        out[r * 48 + lr]      = v0 - lse;
        out[r * 48 + 16 + lr] = v1 - lse;
        out[r * 48 + 32 + lr] = v2 - lse;
    }
}

extern "C" void kernel_launch(void* const* d_in, const int* in_sizes, int n_in,
                              void* d_out, int out_size, void* d_ws, size_t ws_size,
                              hipStream_t stream) {
    const int*   x   = (const int*)d_in[0];
    const float* emb = (const float*)d_in[1];
    const float* wih = (const float*)d_in[2];
    const float* whh = (const float*)d_in[3];
    const float* bhh = (const float*)d_in[4];
    const float* fcw = (const float*)d_in[5];
    const float* fcb = (const float*)d_in[6];
    float* out = (float*)d_out;

    char* ws = (char*)d_ws;
    const size_t off_px    = 0;
    const size_t off_hs    = off_px + (size_t)NROW * Gg * 2;        // 134217728
    const size_t off_hbuf  = off_hs + (size_t)NROW * Hh * 2;        // +33554432
    const size_t off_wih   = off_hbuf + 2 * (size_t)Bb * Hh * 4;    // +262144 (tagged u32)
    const size_t off_fcw   = off_wih + (size_t)Gg * 256 * 2;

    _Float16*     px     = (_Float16*)(ws + off_px);
    unsigned int* hs32   = (unsigned int*)(ws + off_hs);
    unsigned int* hbufT  = (unsigned int*)(ws + off_hbuf);
    short*        wih_bf = (short*)(ws + off_wih);
    short*        fcw_bf = (short*)(ws + off_fcw);

    // tags := 0 every launch (kills stale tags from previous replay)
    hipMemsetAsync(ws + off_hbuf, 0, 2 * (size_t)Bb * Hh * 4, stream);
    prep_bf16<<<512, 256, 0, stream>>>(wih, fcw, wih_bf, fcw_bf);
    px_kernel<<<512, 256, 0, stream>>>(x, emb, wih_bf, bhh, px);

    void* args[] = {(void*)&whh, (void*)&px, (void*)&hbufT, (void*)&hs32};
    hipLaunchCooperativeKernel((void*)lstm_kernel, dim3(32), dim3(512), args, 0, stream);

    fc_kernel<<<512, 256, 0, stream>>>((const unsigned short*)hs32, fcw_bf, fcb, out);
}

// Round 5
// 1901.159 us; speedup vs baseline: 1.0440x; 1.0440x over previous
//
#include <hip/hip_runtime.h>
#include <hip/hip_bf16.h>
#include <hip/hip_fp16.h>

typedef __attribute__((ext_vector_type(8))) short short8;
typedef __attribute__((ext_vector_type(4))) float f32x4;
typedef __attribute__((ext_vector_type(4))) unsigned int u32x4;

#define Hh 512
#define Bb 64
#define Ss 512
#define Gg 2048
#define NROW 32768

static __device__ inline short f2bf(float f) {
    union { float f; unsigned u; } v; v.f = f;
    unsigned r = (v.u + 0x7FFFu + ((v.u >> 16) & 1u)) >> 16;
    return (short)r;
}

static __device__ inline short8 pack_bf8(const float* p) {
    f32x4 u0 = *(const f32x4*)p;
    f32x4 u1 = *(const f32x4*)(p + 4);
    short8 t;
    t[0] = f2bf(u0[0]); t[1] = f2bf(u0[1]); t[2] = f2bf(u0[2]); t[3] = f2bf(u0[3]);
    t[4] = f2bf(u1[0]); t[5] = f2bf(u1[1]); t[6] = f2bf(u1[2]); t[7] = f2bf(u1[3]);
    return t;
}

static __device__ inline float fsigmoid(float x) {
    return __builtin_amdgcn_rcpf(1.f + __builtin_amdgcn_exp2f(x * -1.44269504088896f));
}
static __device__ inline float ftanh(float x) {
    float xc = fminf(fmaxf(x, -15.f), 15.f);
    float e = __builtin_amdgcn_exp2f(xc * 2.88539008177793f); // e^(2x)
    return (e - 1.f) / (e + 1.f);
}

// ---------------- prep: f32 -> bf16 for W_ih and fc_W ----------------
__global__ __launch_bounds__(256)
void prep_bf16(const float* __restrict__ wih, const float* __restrict__ fcw,
               short* __restrict__ wih_bf, short* __restrict__ fcw_bf) {
    const int n1 = Gg * 256;
    const int n2 = 48 * Hh;
    for (int i = blockIdx.x * blockDim.x + threadIdx.x; i < n1 + n2;
         i += gridDim.x * blockDim.x) {
        if (i < n1) wih_bf[i] = f2bf(wih[i]);
        else        fcw_bf[i - n1] = f2bf(fcw[i - n1]);
    }
}

// ---------------- px[t][b][g] = (emb[x] @ W_ih^T + b_hh)  (fp16) ----------------
__global__ __launch_bounds__(256)
void px_kernel(const int* __restrict__ x, const float* __restrict__ emb,
               const short* __restrict__ wih_bf, const float* __restrict__ bhh,
               _Float16* __restrict__ px) {
    const int w = threadIdx.x >> 6, lane = threadIdx.x & 63;
    const int lr = lane & 15, lc = lane >> 4;
    const int r0 = blockIdx.x * 64 + w * 16;

    short8 a[8];
    const int tok = x[r0 + lr];
    const float* arow = emb + (long)tok * 256;
#pragma unroll
    for (int ks = 0; ks < 8; ks++)
        a[ks] = pack_bf8(arow + ks * 32 + lc * 8);

    for (int g0 = 0; g0 < Gg; g0 += 16) {
        f32x4 acc = {0.f, 0.f, 0.f, 0.f};
#pragma unroll
        for (int ks = 0; ks < 8; ks++) {
            short8 b = *(const short8*)(wih_bf + (g0 + lr) * 256 + ks * 32 + lc * 8);
            acc = __builtin_amdgcn_mfma_f32_16x16x32_bf16(a[ks], b, acc, 0, 0, 0);
        }
        const float bias = bhh[g0 + lr];
#pragma unroll
        for (int i = 0; i < 4; i++) {
            const int r = r0 + lc * 4 + i;          // global row = b*S + s
            const int bb = r >> 9, s = r & 511;
            px[((long)s * Bb + bb) * Gg + g0 + lr] = (_Float16)(acc[i] + bias);
        }
    }
}

// ---------------- persistent LSTM recurrence, per-wave flag exchange ----------------
// 32 WGs x 512 thr. cluster cl = blockIdx&3 (16 batches), wgc = blockIdx>>2 (64 cols).
// Producer wave w: stores its 2 h rows, own-wave vmcnt(0) drain, lane0 flag.
// Consumer wave v: polls producer-WG v's 8 wave-flags (one line), stages that 2KB slice.
__global__ __launch_bounds__(512)
void lstm_kernel(const float* __restrict__ whh, const _Float16* __restrict__ px,
                 unsigned int* __restrict__ hbuf32,   // [2][64][256] packed bf16x2
                 unsigned int* __restrict__ hs32,     // [32768][256] packed bf16x2
                 int* __restrict__ flags) {           // [4][8][32] ints (128B/WG group)
    const int cl  = blockIdx.x & 3;
    const int wgc = blockIdx.x >> 2;       // 0..7
    const int b0 = cl * 16;
    const int J0 = wgc * 64;
    const int w = threadIdx.x >> 6;        // 0..7
    const int lane = threadIdx.x & 63;
    const int lr = lane & 15, lc = lane >> 4;
    const int gt = w & 3;
    const int Jsub = (w >> 2) * 32;

    __shared__ float gates[4][16][66];                     // padded
    __shared__ __align__(16) unsigned int hlds[16 * 256];  // 16 KB, swizzled bf16 pairs

    // W_hh fragments resident in VGPRs/AGPRs: 2 tiles x 16 k-steps
    short8 wf[2][16];
#pragma unroll
    for (int u = 0; u < 2; u++)
#pragma unroll
        for (int ks = 0; ks < 16; ks++)
            wf[u][ks] = pack_bf8(whh + (long)(gt * Hh + J0 + Jsub + u * 16 + lr) * Hh + ks * 32 + lc * 8);

    // cell state in registers: thread owns (eb, 2*jp), (eb, 2*jp+1)
    const int eb = threadIdx.x >> 5;       // 0..15 (wave w -> rows 2w, 2w+1)
    const int jp = threadIdx.x & 31;
    float c0 = 0.f, c1 = 0.f;

    const int gr0 = gt * Hh + J0 + Jsub + lr;
    float pf[2][4];
#pragma unroll
    for (int u = 0; u < 2; u++)
#pragma unroll
        for (int i = 0; i < 4; i++)
            pf[u][i] = (float)px[((long)0 * Bb + b0 + lc * 4 + i) * Gg + gr0 + u * 16];

    // staging geometry: wave w consumes producer WG w's 64-col slice
    const int srow = lane & 15;            // batch row
    const int qi   = lane >> 4;            // 0..3
    const int scw  = w * 32 + qi * 8;      // u32 col base within [32w, 32w+32)
    const int ssw  = (srow & 7) << 2;      // XOR swizzle (matches MFMA reads)
    const int sl0  = srow * 256 + (scw ^ ssw);
    const int sl1  = srow * 256 + ((scw + 4) ^ ssw);

    int* const myflag = flags + (cl * 8 + wgc) * 32 + w;
    const int* const pollbase = flags + (cl * 8 + w) * 32;

#pragma unroll 1
    for (int t = 0; t < Ss; t++) {
        if (t == 0) {
            u32x4 z = {0u, 0u, 0u, 0u};
            *(u32x4*)&hlds[sl0] = z;
            *(u32x4*)&hlds[sl1] = z;
        } else {
            // poll producer WG w's 8 wave-flags (one 32B line, replicated load)
            int f;
            do {
                f = __hip_atomic_load(pollbase + (lane & 7), __ATOMIC_RELAXED,
                                      __HIP_MEMORY_SCOPE_AGENT);
            } while (__any(f < t));
            asm volatile("" ::: "memory");   // keep slice loads below the poll

            const unsigned long long* hb = (const unsigned long long*)
                (hbuf32 + (t & 1) * (Bb * Hh / 2) + (b0 + srow) * 256 + scw);
            unsigned long long q0 = __hip_atomic_load(hb + 0, __ATOMIC_RELAXED, __HIP_MEMORY_SCOPE_AGENT);
            unsigned long long q1 = __hip_atomic_load(hb + 1, __ATOMIC_RELAXED, __HIP_MEMORY_SCOPE_AGENT);
            unsigned long long q2 = __hip_atomic_load(hb + 2, __ATOMIC_RELAXED, __HIP_MEMORY_SCOPE_AGENT);
            unsigned long long q3 = __hip_atomic_load(hb + 3, __ATOMIC_RELAXED, __HIP_MEMORY_SCOPE_AGENT);
            u32x4 v0 = {(unsigned)q0, (unsigned)(q0 >> 32), (unsigned)q1, (unsigned)(q1 >> 32)};
            u32x4 v1 = {(unsigned)q2, (unsigned)(q2 >> 32), (unsigned)q3, (unsigned)(q3 >> 32)};
            *(u32x4*)&hlds[sl0] = v0;
            *(u32x4*)&hlds[sl1] = v1;
        }
        __syncthreads();   // A: full h tile staged

        f32x4 acc[2];
#pragma unroll
        for (int u = 0; u < 2; u++) {
            acc[u][0] = pf[u][0]; acc[u][1] = pf[u][1];
            acc[u][2] = pf[u][2]; acc[u][3] = pf[u][3];
        }
#pragma unroll
        for (int ks = 0; ks < 16; ks++) {
            const int c = ks * 16 + lc * 4;
            const short8 af = *(const short8*)&hlds[lr * 256 + (c ^ ((lr & 7) << 2))];
            acc[0] = __builtin_amdgcn_mfma_f32_16x16x32_bf16(af, wf[0][ks], acc[0], 0, 0, 0);
            acc[1] = __builtin_amdgcn_mfma_f32_16x16x32_bf16(af, wf[1][ks], acc[1], 0, 0, 0);
        }

#pragma unroll
        for (int u = 0; u < 2; u++)
#pragma unroll
            for (int i = 0; i < 4; i++)
                gates[gt][lc * 4 + i][Jsub + u * 16 + lr] = acc[u][i];
        __syncthreads();   // B: gates ready

        // elementwise cell update + per-wave h store / drain / flag
        unsigned hpack;
        {
            const int j = jp * 2;
            const float gi0 = gates[0][eb][j],   gi1 = gates[0][eb][j + 1];
            const float gf0 = gates[1][eb][j],   gf1 = gates[1][eb][j + 1];
            const float gg0 = gates[2][eb][j],   gg1 = gates[2][eb][j + 1];
            const float go0 = gates[3][eb][j],   go1 = gates[3][eb][j + 1];
            c0 = fsigmoid(gf0) * c0 + fsigmoid(gi0) * ftanh(gg0);
            c1 = fsigmoid(gf1) * c1 + fsigmoid(gi1) * ftanh(gg1);
            const float h0 = fsigmoid(go0) * ftanh(c0);
            const float h1 = fsigmoid(go1) * ftanh(c1);
            hpack = (unsigned)(unsigned short)f2bf(h0)
                  | ((unsigned)(unsigned short)f2bf(h1) << 16);
            unsigned int* hw = hbuf32 + ((t + 1) & 1) * (Bb * Hh / 2)
                               + (b0 + eb) * 256 + (J0 >> 1) + jp;
            __hip_atomic_store(hw, hpack, __ATOMIC_RELAXED, __HIP_MEMORY_SCOPE_AGENT);
        }
        asm volatile("s_waitcnt vmcnt(0)" ::: "memory");  // own wave's h store acked
        if (lane == 0)
            __hip_atomic_store(myflag, t + 1, __ATOMIC_RELAXED, __HIP_MEMORY_SCOPE_AGENT);

        // off the critical path: history store + px prefetch (drain under next poll)
        hs32[((long)(b0 + eb) * Ss + t) * 256 + (J0 >> 1) + jp] = hpack;
        const int tn = (t + 1 < Ss) ? t + 1 : t;
#pragma unroll
        for (int u = 0; u < 2; u++)
#pragma unroll
            for (int i = 0; i < 4; i++)
                pf[u][i] = (float)px[((long)tn * Bb + b0 + lc * 4 + i) * Gg + gr0 + u * 16];
        asm volatile("" : "+v"(pf[0][0]), "+v"(pf[0][1]), "+v"(pf[0][2]), "+v"(pf[0][3]),
                          "+v"(pf[1][0]), "+v"(pf[1][1]), "+v"(pf[1][2]), "+v"(pf[1][3]));
    }
}

// ---------------- logits = hs @ fc_W^T + fc_b, then log_softmax ----------------
__global__ __launch_bounds__(256)
void fc_kernel(const unsigned short* __restrict__ hs, const short* __restrict__ fcw_bf,
               const float* __restrict__ fcb, float* __restrict__ out) {
    const int w = threadIdx.x >> 6, lane = threadIdx.x & 63;
    const int lr = lane & 15, lc = lane >> 4;
    const int r0 = blockIdx.x * 64 + w * 16;

    short8 af[16];
#pragma unroll
    for (int ks = 0; ks < 16; ks++)
        af[ks] = *(const short8*)((const short*)hs + (long)(r0 + lr) * Hh + ks * 32 + lc * 8);

    f32x4 acc[3];
#pragma unroll
    for (int nt = 0; nt < 3; nt++) {
        f32x4 a_ = {0.f, 0.f, 0.f, 0.f};
#pragma unroll
        for (int ks = 0; ks < 16; ks++) {
            short8 b = *(const short8*)(fcw_bf + (nt * 16 + lr) * Hh + ks * 32 + lc * 8);
            a_ = __builtin_amdgcn_mfma_f32_16x16x32_bf16(af[ks], b, a_, 0, 0, 0);
        }
        acc[nt] = a_;
    }

    const float bb0 = fcb[lr], bb1 = fcb[16 + lr], bb2 = fcb[32 + lr];
#pragma unroll
    for (int i = 0; i < 4; i++) {
        float v0 = acc[0][i] + bb0, v1 = acc[1][i] + bb1, v2 = acc[2][i] + bb2;
        float m = fmaxf(v0, fmaxf(v1, v2));
#pragma unroll
        for (int d = 1; d < 16; d <<= 1) m = fmaxf(m, __shfl_xor(m, d));
        float s = expf(v0 - m) + expf(v1 - m) + expf(v2 - m);
#pragma unroll
        for (int d = 1; d < 16; d <<= 1) s += __shfl_xor(s, d);
        const float lse = m + logf(s);
        const long r = r0 + lc * 4 + i;
        out[r * 48 + lr]      = v0 - lse;
        out[r * 48 + 16 + lr] = v1 - lse;
        out[r * 48 + 32 + lr] = v2 - lse;
    }
}

extern "C" void kernel_launch(void* const* d_in, const int* in_sizes, int n_in,
                              void* d_out, int out_size, void* d_ws, size_t ws_size,
                              hipStream_t stream) {
    const int*   x   = (const int*)d_in[0];
    const float* emb = (const float*)d_in[1];
    const float* wih = (const float*)d_in[2];
    const float* whh = (const float*)d_in[3];
    const float* bhh = (const float*)d_in[4];
    const float* fcw = (const float*)d_in[5];
    const float* fcb = (const float*)d_in[6];
    float* out = (float*)d_out;

    char* ws = (char*)d_ws;
    const size_t off_px    = 0;
    const size_t off_hs    = off_px + (size_t)NROW * Gg * 2;        // 134217728
    const size_t off_hbuf  = off_hs + (size_t)NROW * Hh * 2;        // +33554432
    const size_t off_flags = off_hbuf + 2 * (size_t)Bb * Hh * 2;    // +131072
    const size_t off_wih   = off_flags + 4096;
    const size_t off_fcw   = off_wih + (size_t)Gg * 256 * 2;

    _Float16*     px     = (_Float16*)(ws + off_px);
    unsigned int* hs32   = (unsigned int*)(ws + off_hs);
    unsigned int* hbuf32 = (unsigned int*)(ws + off_hbuf);
    int*          flags  = (int*)(ws + off_flags);
    short*        wih_bf = (short*)(ws + off_wih);
    short*        fcw_bf = (short*)(ws + off_fcw);

    // flags := 0 every launch (h_0 handled in-kernel; hbuf needs no reset)
    hipMemsetAsync(flags, 0, 4096, stream);
    prep_bf16<<<512, 256, 0, stream>>>(wih, fcw, wih_bf, fcw_bf);
    px_kernel<<<512, 256, 0, stream>>>(x, emb, wih_bf, bhh, px);

    void* args[] = {(void*)&whh, (void*)&px, (void*)&hbuf32, (void*)&hs32, (void*)&flags};
    hipLaunchCooperativeKernel((void*)lstm_kernel, dim3(32), dim3(512), args, 0, stream);

    fc_kernel<<<512, 256, 0, stream>>>((const unsigned short*)hs32, fcw_bf, fcb, out);
}

// Round 7
// 1530.553 us; speedup vs baseline: 1.2968x; 1.2421x over previous
//
#include <hip/hip_runtime.h>
#include <hip/hip_bf16.h>
#include <hip/hip_fp16.h>

typedef __attribute__((ext_vector_type(8))) short short8;
typedef __attribute__((ext_vector_type(4))) float f32x4;
typedef __attribute__((ext_vector_type(4))) unsigned int u32x4;

#define Hh 512
#define Bb 64
#define Ss 512
#define Gg 2048
#define NROW 32768

static __device__ inline short f2bf(float f) {
    union { float f; unsigned u; } v; v.f = f;
    unsigned r = (v.u + 0x7FFFu + ((v.u >> 16) & 1u)) >> 16;
    return (short)r;
}

static __device__ inline short8 pack_bf8(const float* p) {
    f32x4 u0 = *(const f32x4*)p;
    f32x4 u1 = *(const f32x4*)(p + 4);
    short8 t;
    t[0] = f2bf(u0[0]); t[1] = f2bf(u0[1]); t[2] = f2bf(u0[2]); t[3] = f2bf(u0[3]);
    t[4] = f2bf(u1[0]); t[5] = f2bf(u1[1]); t[6] = f2bf(u1[2]); t[7] = f2bf(u1[3]);
    return t;
}

static __device__ inline float fsigmoid(float x) {
    return __builtin_amdgcn_rcpf(1.f + __builtin_amdgcn_exp2f(x * -1.44269504088896f));
}
static __device__ inline float ftanh(float x) {
    float xc = fminf(fmaxf(x, -15.f), 15.f);
    float e = __builtin_amdgcn_exp2f(xc * 2.88539008177793f); // e^(2x)
    return (e - 1.f) / (e + 1.f);
}

// ---------------- prep: f32 -> bf16 for W_ih and fc_W ----------------
__global__ __launch_bounds__(256)
void prep_bf16(const float* __restrict__ wih, const float* __restrict__ fcw,
               short* __restrict__ wih_bf, short* __restrict__ fcw_bf) {
    const int n1 = Gg * 256;
    const int n2 = 48 * Hh;
    for (int i = blockIdx.x * blockDim.x + threadIdx.x; i < n1 + n2;
         i += gridDim.x * blockDim.x) {
        if (i < n1) wih_bf[i] = f2bf(wih[i]);
        else        fcw_bf[i - n1] = f2bf(fcw[i - n1]);
    }
}

// ---------------- px[t][b][g] = (emb[x] @ W_ih^T + b_hh)  (fp16) ----------------
__global__ __launch_bounds__(256)
void px_kernel(const int* __restrict__ x, const float* __restrict__ emb,
               const short* __restrict__ wih_bf, const float* __restrict__ bhh,
               _Float16* __restrict__ px) {
    const int w = threadIdx.x >> 6, lane = threadIdx.x & 63;
    const int lr = lane & 15, lc = lane >> 4;
    const int r0 = blockIdx.x * 64 + w * 16;

    short8 a[8];
    const int tok = x[r0 + lr];
    const float* arow = emb + (long)tok * 256;
#pragma unroll
    for (int ks = 0; ks < 8; ks++)
        a[ks] = pack_bf8(arow + ks * 32 + lc * 8);

    for (int g0 = 0; g0 < Gg; g0 += 16) {
        f32x4 acc = {0.f, 0.f, 0.f, 0.f};
#pragma unroll
        for (int ks = 0; ks < 8; ks++) {
            short8 b = *(const short8*)(wih_bf + (g0 + lr) * 256 + ks * 32 + lc * 8);
            acc = __builtin_amdgcn_mfma_f32_16x16x32_bf16(a[ks], b, acc, 0, 0, 0);
        }
        const float bias = bhh[g0 + lr];
#pragma unroll
        for (int i = 0; i < 4; i++) {
            const int r = r0 + lc * 4 + i;          // global row = b*S + s
            const int bb = r >> 9, s = r & 511;
            px[((long)s * Bb + bb) * Gg + g0 + lr] = (_Float16)(acc[i] + bias);
        }
    }
}

// ---------------- persistent LSTM recurrence (R3 topology, chain-trimmed) ----------------
// 32 WGs x 512 thr. cluster cl = blockIdx&3 (16 batches), wgc = blockIdx>>2 (64 cols).
// Per-wave poll of the cluster's 8 WG-flags (one 32B line), then each thread stages its
// 32B of the 16KB h tile in ONE L3 round trip into sigma-swizzled LDS.
__global__ __launch_bounds__(512)
void lstm_kernel(const float* __restrict__ whh, const _Float16* __restrict__ px,
                 unsigned int* __restrict__ hbuf32,   // [2][64][256] packed bf16x2
                 unsigned int* __restrict__ hs32,     // [32768][256] packed bf16x2
                 int* __restrict__ flags) {           // [4][32] ints
    const int cl  = blockIdx.x & 3;
    const int wgc = blockIdx.x >> 2;       // 0..7
    const int b0 = cl * 16;
    const int J0 = wgc * 64;
    const int tid = threadIdx.x;
    const int w = tid >> 6;                // 0..7
    const int lane = tid & 63;
    const int lr = lane & 15, lc = lane >> 4;
    const int gt = w & 3;
    const int Jsub = (w >> 2) * 32;

    __shared__ float gates[4][16][66];                     // padded (2-way max)
    __shared__ __align__(16) unsigned int hlds[16 * 256];  // 16 KB, sigma-swizzled

    // W_hh fragments resident in AGPRs: 2 tiles x 16 k-steps (128 regs)
    short8 wf[2][16];
#pragma unroll
    for (int u = 0; u < 2; u++)
#pragma unroll
        for (int ks = 0; ks < 16; ks++)
            wf[u][ks] = pack_bf8(whh + (long)(gt * Hh + J0 + Jsub + u * 16 + lr) * Hh + ks * 32 + lc * 8);

    // cell state in registers: thread owns (eb, 2*jp), (eb, 2*jp+1)
    const int eb = tid >> 5;               // 0..15
    const int jp = tid & 31;
    float c0 = 0.f, c1 = 0.f;

    const int gr0 = gt * Hh + J0 + Jsub + lr;

    // staging geometry: thread -> (row = tid>>5, colgroup = tid&31), 32B each.
    // sigma-swizzle chunk: chi(q,row) = q ^ ((q>>3)&7) ^ (row&7)   (involution)
    const int srow = tid >> 5;             // 0..15
    const int scg  = tid & 31;             // 32B group
    const int q0c  = 2 * scg;
    const int chi0 = (q0c ^ ((q0c >> 3) & 7) ^ (srow & 7));
    const int sidx0 = srow * 256 + chi0 * 4;
    const int sidx1 = srow * 256 + (chi0 ^ 1) * 4;

    int* const myflag = flags + cl * 32 + wgc;
    const int* const pollbase = flags + cl * 32;

    // px double-buffer (static names; unroll-by-2 keeps indices compile-time)
    float pfA[2][4], pfB[2][4];
#pragma unroll
    for (int u = 0; u < 2; u++)
#pragma unroll
        for (int i = 0; i < 4; i++)
            pfA[u][i] = (float)px[((long)0 * Bb + b0 + lc * 4 + i) * Gg + gr0 + u * 16];

#define LSTM_STEP(T, PFU, PFN)                                                         \
    {                                                                                  \
        const int T_ = (T);                                                            \
        if (T_ == 0) {                                                                 \
            u32x4 z = {0u, 0u, 0u, 0u};                                                \
            *(u32x4*)&hlds[sidx0] = z;                                                 \
            *(u32x4*)&hlds[sidx1] = z;                                                 \
        } else {                                                                       \
            const int* fp = pollbase + (lane & 7);                                     \
            int fv = __hip_atomic_load(fp, __ATOMIC_RELAXED, __HIP_MEMORY_SCOPE_AGENT);\
            while (__any(fv < T_))                                                     \
                fv = __hip_atomic_load(fp, __ATOMIC_RELAXED, __HIP_MEMORY_SCOPE_AGENT);\
            asm volatile("" ::: "memory");                                             \
            const unsigned long long* hb = (const unsigned long long*)                 \
                (hbuf32 + (T_ & 1) * (Bb * Hh / 2) + (b0 + srow) * 256 + scg * 8);     \
            unsigned long long a0 = __hip_atomic_load(hb + 0, __ATOMIC_RELAXED, __HIP_MEMORY_SCOPE_AGENT); \
            unsigned long long a1 = __hip_atomic_load(hb + 1, __ATOMIC_RELAXED, __HIP_MEMORY_SCOPE_AGENT); \
            unsigned long long a2 = __hip_atomic_load(hb + 2, __ATOMIC_RELAXED, __HIP_MEMORY_SCOPE_AGENT); \
            unsigned long long a3 = __hip_atomic_load(hb + 3, __ATOMIC_RELAXED, __HIP_MEMORY_SCOPE_AGENT); \
            u32x4 v0 = {(unsigned)a0, (unsigned)(a0 >> 32), (unsigned)a1, (unsigned)(a1 >> 32)}; \
            u32x4 v1 = {(unsigned)a2, (unsigned)(a2 >> 32), (unsigned)a3, (unsigned)(a3 >> 32)}; \
            *(u32x4*)&hlds[sidx0] = v0;                                                \
            *(u32x4*)&hlds[sidx1] = v1;                                                \
        }                                                                              \
        __syncthreads(); /* A: h tile staged */                                        \
        f32x4 acc0, acc1;                                                              \
        _Pragma("unroll")                                                              \
        for (int i = 0; i < 4; i++) { acc0[i] = PFU[0][i]; acc1[i] = PFU[1][i]; }      \
        _Pragma("unroll")                                                              \
        for (int ks = 0; ks < 16; ks++) {                                              \
            const int q = ks * 4 + lc;                                                 \
            const int chi = q ^ ((q >> 3) & 7) ^ (lr & 7);                             \
            const short8 af = *(const short8*)&hlds[lr * 256 + chi * 4];               \
            acc0 = __builtin_amdgcn_mfma_f32_16x16x32_bf16(af, wf[0][ks], acc0, 0, 0, 0); \
            acc1 = __builtin_amdgcn_mfma_f32_16x16x32_bf16(af, wf[1][ks], acc1, 0, 0, 0); \
        }                                                                              \
        _Pragma("unroll")                                                              \
        for (int i = 0; i < 4; i++) {                                                  \
            gates[gt][lc * 4 + i][Jsub + lr]      = acc0[i];                           \
            gates[gt][lc * 4 + i][Jsub + 16 + lr] = acc1[i];                           \
        }                                                                              \
        __syncthreads(); /* B: gates ready */                                          \
        unsigned hpack;                                                                \
        {                                                                              \
            const float2 gI = *(const float2*)&gates[0][eb][jp * 2];                   \
            const float2 gF = *(const float2*)&gates[1][eb][jp * 2];                   \
            const float2 gG = *(const float2*)&gates[2][eb][jp * 2];                   \
            const float2 gO = *(const float2*)&gates[3][eb][jp * 2];                   \
            c0 = fsigmoid(gF.x) * c0 + fsigmoid(gI.x) * ftanh(gG.x);                   \
            c1 = fsigmoid(gF.y) * c1 + fsigmoid(gI.y) * ftanh(gG.y);                   \
            const float h0 = fsigmoid(gO.x) * ftanh(c0);                               \
            const float h1 = fsigmoid(gO.y) * ftanh(c1);                               \
            hpack = (unsigned)(unsigned short)f2bf(h0)                                 \
                  | ((unsigned)(unsigned short)f2bf(h1) << 16);                        \
            unsigned int* hw = hbuf32 + ((T_ + 1) & 1) * (Bb * Hh / 2)                 \
                               + (b0 + eb) * 256 + (J0 >> 1) + jp;                     \
            __hip_atomic_store(hw, hpack, __ATOMIC_RELAXED, __HIP_MEMORY_SCOPE_AGENT); \
        }                                                                              \
        __syncthreads(); /* C: all h stores drained (vmcnt0 before barrier) */         \
        if (tid == 0)                                                                  \
            __hip_atomic_store(myflag, T_ + 1, __ATOMIC_RELAXED, __HIP_MEMORY_SCOPE_AGENT); \
        hs32[((long)(b0 + eb) * Ss + T_) * 256 + (J0 >> 1) + jp] = hpack;              \
        const int tn = (T_ + 1 < Ss) ? T_ + 1 : T_;                                    \
        _Pragma("unroll")                                                              \
        for (int u = 0; u < 2; u++)                                                    \
            _Pragma("unroll")                                                          \
            for (int i = 0; i < 4; i++)                                                \
                PFN[u][i] = (float)px[((long)tn * Bb + b0 + lc * 4 + i) * Gg + gr0 + u * 16]; \
    }

#pragma unroll 1
    for (int t = 0; t < Ss; t += 2) {
        LSTM_STEP(t,     pfA, pfB)
        LSTM_STEP(t + 1, pfB, pfA)
    }
#undef LSTM_STEP
}

// ---------------- logits = hs @ fc_W^T + fc_b, then log_softmax ----------------
__global__ __launch_bounds__(256)
void fc_kernel(const unsigned short* __restrict__ hs, const short* __restrict__ fcw_bf,
               const float* __restrict__ fcb, float* __restrict__ out) {
    const int w = threadIdx.x >> 6, lane = threadIdx.x & 63;
    const int lr = lane & 15, lc = lane >> 4;
    const int r0 = blockIdx.x * 64 + w * 16;

    short8 af[16];
#pragma unroll
    for (int ks = 0; ks < 16; ks++)
        af[ks] = *(const short8*)((const short*)hs + (long)(r0 + lr) * Hh + ks * 32 + lc * 8);

    f32x4 acc[3];
#pragma unroll
    for (int nt = 0; nt < 3; nt++) {
        f32x4 a_ = {0.f, 0.f, 0.f, 0.f};
#pragma unroll
        for (int ks = 0; ks < 16; ks++) {
            short8 b = *(const short8*)(fcw_bf + (nt * 16 + lr) * Hh + ks * 32 + lc * 8);
            a_ = __builtin_amdgcn_mfma_f32_16x16x32_bf16(af[ks], b, a_, 0, 0, 0);
        }
        acc[nt] = a_;
    }

    const float bb0 = fcb[lr], bb1 = fcb[16 + lr], bb2 = fcb[32 + lr];
#pragma unroll
    for (int i = 0; i < 4; i++) {
        float v0 = acc[0][i] + bb0, v1 = acc[1][i] + bb1, v2 = acc[2][i] + bb2;
        float m = fmaxf(v0, fmaxf(v1, v2));
#pragma unroll
        for (int d = 1; d < 16; d <<= 1) m = fmaxf(m, __shfl_xor(m, d));
        float s = expf(v0 - m) + expf(v1 - m) + expf(v2 - m);
#pragma unroll
        for (int d = 1; d < 16; d <<= 1) s += __shfl_xor(s, d);
        const float lse = m + logf(s);
        const long r = r0 + lc * 4 + i;
        out[r * 48 + lr]      = v0 - lse;
        out[r * 48 + 16 + lr] = v1 - lse;
        out[r * 48 + 32 + lr] = v2 - lse;
    }
}

extern "C" void kernel_launch(void* const* d_in, const int* in_sizes, int n_in,
                              void* d_out, int out_size, void* d_ws, size_t ws_size,
                              hipStream_t stream) {
    const int*   x   = (const int*)d_in[0];
    const float* emb = (const float*)d_in[1];
    const float* wih = (const float*)d_in[2];
    const float* whh = (const float*)d_in[3];
    const float* bhh = (const float*)d_in[4];
    const float* fcw = (const float*)d_in[5];
    const float* fcb = (const float*)d_in[6];
    float* out = (float*)d_out;

    char* ws = (char*)d_ws;
    const size_t off_px    = 0;
    const size_t off_hs    = off_px + (size_t)NROW * Gg * 2;        // 134217728
    const size_t off_hbuf  = off_hs + (size_t)NROW * Hh * 2;        // +33554432
    const size_t off_flags = off_hbuf + 2 * (size_t)Bb * Hh * 2;    // +131072
    const size_t off_wih   = off_flags + 4096;
    const size_t off_fcw   = off_wih + (size_t)Gg * 256 * 2;

    _Float16*     px     = (_Float16*)(ws + off_px);
    unsigned int* hs32   = (unsigned int*)(ws + off_hs);
    unsigned int* hbuf32 = (unsigned int*)(ws + off_hbuf);
    int*          flags  = (int*)(ws + off_flags);
    short*        wih_bf = (short*)(ws + off_wih);
    short*        fcw_bf = (short*)(ws + off_fcw);

    // flags := 0 every launch (h_0 is zeroed in-kernel; hbuf needs no reset)
    hipMemsetAsync(flags, 0, 4096, stream);
    prep_bf16<<<512, 256, 0, stream>>>(wih, fcw, wih_bf, fcw_bf);
    px_kernel<<<512, 256, 0, stream>>>(x, emb, wih_bf, bhh, px);

    void* args[] = {(void*)&whh, (void*)&px, (void*)&hbuf32, (void*)&hs32, (void*)&flags};
    hipLaunchCooperativeKernel((void*)lstm_kernel, dim3(32), dim3(512), args, 0, stream);

    fc_kernel<<<512, 256, 0, stream>>>((const unsigned short*)hs32, fcw_bf, fcb, out);
}